// Round 14
// baseline (431.240 us; speedup 1.0000x reference)
//
#include <hip/hip_runtime.h>
#include <hip/hip_bf16.h>

#define B_ 128
#define N_ 1024
#define E_ 300
#define U_ 128
#define M_ (B_ * N_)   // 131072
#define Z_ (5 * U_)    // 640
#define LMAXT 40       // level buckets (last = overflow, t-ordered)
#define LPAR 12        // levels 1..LPAR-1 parallel GEMMs; rest in tail

typedef __attribute__((ext_vector_type(8))) short bf16x8;
typedef __attribute__((ext_vector_type(4))) float f32x4;
typedef _Float16 f16x4 __attribute__((ext_vector_type(4)));
typedef _Float16 f16x8 __attribute__((ext_vector_type(8)));

__device__ __forceinline__ short f2bf(float f) {
  unsigned u = __builtin_bit_cast(unsigned, f);
  u = (u + 0x7fffu + ((u >> 16) & 1u)) >> 16;
  return (short)u;
}

__device__ __forceinline__ float hsig(float z) {
  float v = __builtin_fmaf(z, 0.2f, 0.5f);
  v = v < 0.f ? 0.f : v;
  v = v > 1.f ? 1.f : v;
  return v;
}

__device__ __forceinline__ float tanh_fast(float x) {
  float p = __expf(2.f * x);
  return 1.f - 2.f * __builtin_amdgcn_rcpf(p + 1.f);
}

__device__ __forceinline__ unsigned pk2(float a, float b) {
  return __builtin_bit_cast(unsigned, __builtin_amdgcn_cvt_pkrtz(a, b));
}

__device__ __forceinline__ f16x8 pack8(float4 a, float4 b) {
  uint4 u;
  u.x = pk2(a.x, a.y);
  u.y = pk2(a.z, a.w);
  u.z = pk2(b.x, b.y);
  u.w = pk2(b.z, b.w);
  return __builtin_bit_cast(f16x8, u);
}

// ---------------- Kernel P: weight prep ------------------------------------
// W16: Wr f16 (640,256); Wk16: kernel f16 (640,128); tkTb: tk^T bf16
// (128 rows x 320 k, zero-padded) so x_gemm W-staging is 2 vector loads.
__global__ __launch_bounds__(256) void prep(
    const float* __restrict__ Wr, const float* __restrict__ Wk,
    const float* __restrict__ tk, _Float16* __restrict__ W16,
    _Float16* __restrict__ Wk16, short* __restrict__ tkTb) {
  const int idx = blockIdx.x * 256 + threadIdx.x;
  if (idx < 163840) {
    W16[idx] = (_Float16)Wr[idx];
  } else if (idx < 245760) {
    const int i = idx - 163840;
    Wk16[i] = (_Float16)Wk[i];
  } else if (idx < 286720) {
    const int i = idx - 245760;
    const int n = i / 320, k = i - n * 320;
    tkTb[i] = (k < E_) ? f2bf(tk[k * U_ + n]) : (short)0;
  }
}

// ---------------- Kernel 1: x = relu(state @ Tk) -> H (vector W-staging) ---
__global__ __launch_bounds__(256) void x_gemm(
    const float* __restrict__ A, const short* __restrict__ tkTb,
    float* __restrict__ H) {
  __shared__ __align__(16) short As[64][40];
  __shared__ __align__(16) short Ws[128][40];
  const int tid = threadIdx.x;
  const int m0 = blockIdx.x * 64;
  f32x4 acc[8] = {};
  const int lane = tid & 63, wv = tid >> 6;
  const int lr = lane & 15, lg = lane >> 4;

  for (int kc = 0; kc < 10; ++kc) {
    const int k0 = kc * 32;
    {
      const int row = tid >> 2, kk = (tid & 3) * 8;
      const float* src = A + (size_t)(m0 + row) * E_ + k0 + kk;
      bf16x8 v;
      if (k0 + 32 <= E_) {
#pragma unroll
        for (int i = 0; i < 8; ++i) v[i] = f2bf(src[i]);
      } else {
#pragma unroll
        for (int i = 0; i < 8; ++i)
          v[i] = (k0 + kk + i < E_) ? f2bf(src[i]) : (short)0;
      }
      *(bf16x8*)&As[row][kk] = v;
    }
#pragma unroll
    for (int s = 0; s < 2; ++s) {
      const int slot = tid + s * 256;
      const int n = slot & 127, kg = slot >> 7;
      *(bf16x8*)&Ws[n][kg * 8] =
          *(const bf16x8*)(tkTb + (size_t)n * 320 + k0 + kg * 8);
    }
    __syncthreads();
    bf16x8 a = *(const bf16x8*)&As[wv * 16 + lr][lg * 8];
#pragma unroll
    for (int nt = 0; nt < 8; ++nt) {
      bf16x8 b = *(const bf16x8*)&Ws[nt * 16 + lr][lg * 8];
      acc[nt] = __builtin_amdgcn_mfma_f32_16x16x32_bf16(a, b, acc[nt], 0, 0, 0);
    }
    __syncthreads();
  }
#pragma unroll
  for (int nt = 0; nt < 8; ++nt) {
#pragma unroll
    for (int r = 0; r < 4; ++r) {
      const int m = m0 + wv * 16 + lg * 4 + r;
      const int n = nt * 16 + lr;
      float v = acc[nt][r];
      v = v > 0.f ? v : 0.f;
      H[(size_t)m * U_ + n] = v;
    }
  }
}

// ---------------- Kernel S: f16 shadows H16, C16 from H --------------------
// Leaf c == x == h, and internal rows get overwritten by level kernels, so
// one pass over H covers both shadows.
__global__ __launch_bounds__(256) void h16c16(
    const float* __restrict__ H, _Float16* __restrict__ H16,
    _Float16* __restrict__ C16) {
  const size_t i = ((size_t)blockIdx.x * 256 + threadIdx.x) * 8;
  if (i < (size_t)M_ * U_) {
    const float4 a0 = *(const float4*)(H + i);
    const float4 a1 = *(const float4*)(H + i + 4);
    const f16x8 v = pack8(a0, a1);
    *(f16x8*)(H16 + i) = v;
    *(f16x8*)(C16 + i) = v;
  }
}

// ---------------- Kernel 2: xz = x @ K^T + bias (f16 staged + stores) ------
__global__ __launch_bounds__(256) void xz_gemm(
    const float* __restrict__ X, const _Float16* __restrict__ Wk16,
    const float* __restrict__ bias, const int* __restrict__ nv,
    _Float16* __restrict__ XZ) {
  const int m0 = blockIdx.x * 64;
  {
    const int bb = m0 >> 10;
    const int t0 = m0 & (N_ - 1);
    const int nodes = nv[2 * bb], leaves = nv[2 * bb + 1];
    if (t0 + 64 <= leaves || t0 >= nodes) return;
  }
  __shared__ __align__(16) short As[64][40];
  __shared__ __align__(16) short Ws[128][40];
  __shared__ __align__(16) _Float16 xzls[64][136];
  const int tid = threadIdx.x;
  const int n0 = blockIdx.y * 128;
  f32x4 acc[8] = {};
  const int lane = tid & 63, wv = tid >> 6;
  const int lr = lane & 15, lg = lane >> 4;

  for (int kc = 0; kc < 4; ++kc) {
    const int k0 = kc * 32;
    {
      const int row = tid >> 2, kk = (tid & 3) * 8;
      const float* src = X + (size_t)(m0 + row) * U_ + k0 + kk;
      const float4 a0 = *(const float4*)src;
      const float4 a1 = *(const float4*)(src + 4);
      *(f16x8*)&As[row][kk] = pack8(a0, a1);
    }
#pragma unroll
    for (int s = 0; s < 2; ++s) {
      const int slot = tid + s * 256;
      const int n = slot >> 2, kk = (slot & 3) * 8;
      *(f16x8*)&Ws[n][kk] =
          *(const f16x8*)(Wk16 + (size_t)(n0 + n) * U_ + k0 + kk);
    }
    __syncthreads();
    f16x8 a = *(const f16x8*)&As[wv * 16 + lr][lg * 8];
#pragma unroll
    for (int nt = 0; nt < 8; ++nt) {
      f16x8 b = *(const f16x8*)&Ws[nt * 16 + lr][lg * 8];
      acc[nt] = __builtin_amdgcn_mfma_f32_16x16x32_f16(a, b, acc[nt], 0, 0, 0);
    }
    __syncthreads();
  }
#pragma unroll
  for (int nt = 0; nt < 8; ++nt) {
    const float bv = bias[n0 + nt * 16 + lr];
#pragma unroll
    for (int r = 0; r < 4; ++r)
      xzls[wv * 16 + lg * 4 + r][nt * 16 + lr] = (_Float16)(acc[nt][r] + bv);
  }
  __syncthreads();
  {
    const int row = tid >> 2, c0 = (tid & 3) * 32;
    _Float16* dst = XZ + (size_t)(m0 + row) * Z_ + n0 + c0;
#pragma unroll
    for (int s = 0; s < 4; ++s)
      *(f16x8*)(dst + 8 * s) = *(const f16x8*)&xzls[row][c0 + 8 * s];
  }
}

// ---------------- Kernel C1: per-batch levelize (parallel fixpoint) --------
__global__ __launch_bounds__(512) void levelize(
    const int* __restrict__ child, const int* __restrict__ nv,
    unsigned char* __restrict__ lv, short* __restrict__ rank,
    int* __restrict__ cnt) {
  const int b = blockIdx.x;
  const int tid = threadIdx.x;
  int nodes = nv[2 * b];
  int leaves = nv[2 * b + 1];
  if (nodes > N_) nodes = N_;
  if (leaves < 0) leaves = 0;

  __shared__ short lvs[N_];
  __shared__ int chs[2 * N_];
  __shared__ int cnts[LMAXT];
  __shared__ int changed;

  for (int i = tid; i < N_; i += 512) lvs[i] = 0;
  for (int i = tid; i < 2 * N_; i += 512) chs[i] = child[(size_t)b * 2 * N_ + i];
  if (tid < LMAXT) cnts[tid] = 0;
  __syncthreads();

  int stable = 0;
  for (int s = 0; s < 64; ++s) {
    if (tid == 0) changed = 0;
    __syncthreads();
    int any = 0;
    for (int t = leaves + tid; t < nodes; t += 512) {
      const int c0 = chs[2 * t], c1 = chs[2 * t + 1];
      const int l0 = (c0 < t && c0 >= 0) ? lvs[c0] : 0;
      const int l1 = (c1 < t && c1 >= 0) ? lvs[c1] : 0;
      const int l = 1 + (l0 > l1 ? l0 : l1);
      if (l > (int)lvs[t]) { lvs[t] = (short)l; any = 1; }
    }
    if (any) changed = 1;
    __syncthreads();
    if (!changed) { stable = 1; break; }
  }
  if (!stable) {
    if (tid == 0) {
      for (int t = leaves; t < nodes; ++t) {
        const int c0 = chs[2 * t], c1 = chs[2 * t + 1];
        const int l0 = (c0 < t && c0 >= 0) ? lvs[c0] : 0;
        const int l1 = (c1 < t && c1 >= 0) ? lvs[c1] : 0;
        lvs[t] = (short)(1 + (l0 > l1 ? l0 : l1));
      }
    }
    __syncthreads();
  }

  for (int t = tid; t < nodes; t += 512) {
    int l = (t < leaves) ? 0 : (int)lvs[t];
    if (l > LMAXT - 1) l = LMAXT - 1;
    lv[b * N_ + t] = (unsigned char)l;
    if (t >= leaves && l < LMAXT - 1)
      rank[b * N_ + t] = (short)atomicAdd(&cnts[l], 1);
  }
  __syncthreads();
  if (tid == 0) {
    for (int t = leaves; t < nodes; ++t)
      if ((int)lvs[t] >= LMAXT - 1) rank[b * N_ + t] = (short)(cnts[LMAXT - 1]++);
  }
  __syncthreads();
  if (tid < LMAXT) cnt[tid * 128 + b] = cnts[tid];
}

// ---------------- Kernel C2: global offsets --------------------------------
__global__ __launch_bounds__(64) void offsets(
    const int* __restrict__ cnt, int* __restrict__ pos, int* __restrict__ goff) {
  const int l = threadIdx.x;
  __shared__ int tot[LMAXT];
  if (l < LMAXT) {
    int s = 0;
    for (int b = 0; b < 128; ++b) {
      pos[l * 128 + b] = s;
      s += cnt[l * 128 + b];
    }
    tot[l] = s;
  }
  __syncthreads();
  if (l == 0) {
    int g = 0;
    for (int i = 0; i < LMAXT; ++i) { goff[i] = g; g += tot[i]; }
    goff[LMAXT] = g;
  }
  __syncthreads();
  if (l < LMAXT) {
    const int g = goff[l];
    for (int b = 0; b < 128; ++b) pos[l * 128 + b] += g;
  }
}

// ---------------- Kernel C3: scatter node list + zero invalid rows ---------
__global__ __launch_bounds__(256) void scatter_zero(
    const int* __restrict__ nv, const unsigned char* __restrict__ lv,
    const short* __restrict__ rank, const int* __restrict__ pos,
    int* __restrict__ glist, float* __restrict__ H) {
  const int b = blockIdx.x;
  const int tid = threadIdx.x;
  int nodes = nv[2 * b];
  int leaves = nv[2 * b + 1];
  if (nodes > N_) nodes = N_;
  if (leaves < 0) leaves = 0;
  for (int t = leaves + tid; t < nodes; t += 256) {
    const int l = lv[b * N_ + t];
    glist[pos[l * 128 + b] + rank[b * N_ + t]] = (b << 10) | t;
  }
  const int total = (N_ - nodes) * U_;
  for (int idx = tid; idx < total; idx += 256)
    H[(size_t)b * N_ * U_ + nodes * U_ + idx] = 0.f;
}

// ---------------- chunk-load helper for level_gemm (f16 gathers) -----------
struct ChunkLd {
  uint4 h16;    // 8 f16 of h_ch (per-lane j,s)
  f16x8 cv16;   // 8 f16 of c_ch (per-lane col)
  f16x4 xzi, xzo, xzg;
  f16x8 xzf;
  int nid, rem;
};

__device__ __forceinline__ ChunkLd load_chunk(
    int chunk, int nchunk, int base, int count, const int* __restrict__ glist,
    const int* __restrict__ child, const _Float16* __restrict__ XZ,
    const _Float16* __restrict__ H16, const _Float16* __restrict__ C16,
    int j, int s, int col, int u0, int mc) {
  ChunkLd r;
  const int cc = chunk < nchunk - 1 ? chunk : nchunk - 1;
  const int cb = base + cc * 16;
  int rem = count - cc * 16;
  if (rem > 16) rem = 16;
  r.rem = rem;

  const int nidj = glist[cb + (j < rem ? j : rem - 1)];
  const int bj = nidj >> 10, tj = nidj & 1023;
  const int chj = child[((size_t)bj << 11) + 2 * tj + (s >> 4)];
  r.h16 = *(const uint4*)(H16 + (((size_t)(bj << 10) + chj) << 7) +
                          ((s & 15) << 3));

  const int nidc = glist[cb + (col < rem ? col : rem - 1)];
  r.nid = nidc;
  const _Float16* xzr = XZ + (size_t)nidc * Z_;
  r.xzi = *(const f16x4*)(xzr + u0);
  r.xzf = *(const f16x8*)(xzr + 128 + mc);
  r.xzo = *(const f16x4*)(xzr + 384 + u0);
  r.xzg = *(const f16x4*)(xzr + 512 + u0);
  const int bc = nidc >> 10, tc = nidc & 1023;
  const int csel = child[((size_t)bc << 11) + 2 * tc + (mc >> 7)];
  const int crow = (bc << 10) | csel;
  r.cv16 = *(const f16x8*)(C16 + ((size_t)crow << 7) + (mc & 127));
  return r;
}

// ---------------- Kernel L: one level, pipelined chunks, no vmcnt drain ----
__global__ __launch_bounds__(512, 2) void level_gemm(
    int lvl, const _Float16* __restrict__ W16, const int* __restrict__ child,
    const int* __restrict__ goff, const int* __restrict__ glist,
    const _Float16* __restrict__ XZ, float* __restrict__ H,
    _Float16* __restrict__ H16, _Float16* __restrict__ C16) {
  const int base = goff[lvl];
  const int count = goff[lvl + 1] - base;
  if (count <= 0) return;
  const int nchunk = (count + 15) >> 4;
  if ((int)blockIdx.x >= nchunk) return;
  const int tid = threadIdx.x;
  const int lane = tid & 63, w = tid >> 6;
  const int col = lane & 15, hi = lane >> 4;
  const int u0 = 16 * w + 4 * hi;
  const int mc = 2 * u0;
  const int j = tid >> 5, s = tid & 31;

  f16x8 afrag[5][8];
  {
    const int rows[5] = {16 * w + col, 128 + 32 * w + 2 * col,
                         129 + 32 * w + 2 * col, 384 + 16 * w + col,
                         512 + 16 * w + col};
#pragma unroll
    for (int rt = 0; rt < 5; ++rt) {
      const _Float16* rs = W16 + (size_t)rows[rt] * 256 + 8 * hi;
#pragma unroll
      for (int kt = 0; kt < 8; ++kt) afrag[rt][kt] = *(const f16x8*)(rs + 32 * kt);
    }
  }

  __shared__ __align__(16) _Float16 hbuf[2][16][272];

  ChunkLd cur = load_chunk(blockIdx.x, nchunk, base, count, glist, child, XZ,
                           H16, C16, j, s, col, u0, mc);
  int p = 0;
  for (int chunk = blockIdx.x; chunk < nchunk; chunk += gridDim.x) {
    // stage h into hbuf[p] (counted vmcnt for cur only)
    *(uint4*)&hbuf[p][j][(s >> 4) * 128 + (s & 15) * 8] = cur.h16;

    // issue next chunk's gathers (stay in flight across the barrier)
    ChunkLd nxt = load_chunk(chunk + gridDim.x < nchunk ? chunk + gridDim.x
                                                        : nchunk - 1,
                             nchunk, base, count, glist, child, XZ, H16, C16,
                             j, s, col, u0, mc);

    // raw barrier: LDS visibility only, no vmcnt drain
    asm volatile("s_waitcnt lgkmcnt(0)" ::: "memory");
    __builtin_amdgcn_sched_barrier(0);
    __builtin_amdgcn_s_barrier();
    __builtin_amdgcn_sched_barrier(0);

    f32x4 acc[5];
#pragma unroll
    for (int r = 0; r < 4; ++r) {
      acc[0][r] = (float)cur.xzi[r];
      acc[1][r] = (float)cur.xzf[2 * r];
      acc[2][r] = (float)cur.xzf[2 * r + 1];
      acc[3][r] = (float)cur.xzo[r];
      acc[4][r] = (float)cur.xzg[r];
    }
#pragma unroll
    for (int kt = 0; kt < 8; ++kt) {
      const f16x8 bf = *(const f16x8*)&hbuf[p][col][32 * kt + 8 * hi];
#pragma unroll
      for (int rt = 0; rt < 5; ++rt)
        acc[rt] = __builtin_amdgcn_mfma_f32_16x16x32_f16(afrag[rt][kt], bf,
                                                         acc[rt], 0, 0, 0);
    }

    f32x4 hn4, cn4;
#pragma unroll
    for (int r = 0; r < 4; ++r) {
      const float cn = (float)cur.cv16[2 * r] * hsig(acc[1][r]) +
                       (float)cur.cv16[2 * r + 1] * hsig(acc[2][r]) +
                       hsig(acc[0][r]) * tanh_fast(acc[4][r]);
      cn4[r] = cn;
      hn4[r] = hsig(acc[3][r]) * tanh_fast(cn);
    }
    if (col < cur.rem) {
      const size_t rowb = (size_t)cur.nid << 7;
      *(f32x4*)(H + rowb + u0) = hn4;
      uint2 hp16, cp16;
      hp16.x = pk2(hn4[0], hn4[1]);
      hp16.y = pk2(hn4[2], hn4[3]);
      cp16.x = pk2(cn4[0], cn4[1]);
      cp16.y = pk2(cn4[2], cn4[3]);
      *(uint2*)(H16 + rowb + u0) = hp16;
      *(uint2*)(C16 + rowb + u0) = cp16;
    }
    cur = nxt;
    p ^= 1;
  }
}

// ---------------- Kernel T: sequential tail for levels >= LPAR -------------
__global__ __launch_bounds__(512, 2) void tail_scan(
    const _Float16* __restrict__ W16, const int* __restrict__ child,
    const int* __restrict__ nv, const int* __restrict__ pos,
    const int* __restrict__ cnt, const int* __restrict__ glist,
    const _Float16* __restrict__ XZ, float* __restrict__ H,
    _Float16* __restrict__ H16, _Float16* __restrict__ C16) {
  const int b = blockIdx.x;
  const int tid = threadIdx.x;
  const int lane = tid & 63, w = tid >> 6;
  const int col = lane & 15, hi = lane >> 4;
  const int u0 = 16 * w + 4 * hi;
  const int mc = 2 * u0;
  const int m4 = 4 * lane;

  f16x8 afrag[5][8];
  {
    const int rows[5] = {16 * w + col, 128 + 32 * w + 2 * col,
                         129 + 32 * w + 2 * col, 384 + 16 * w + col,
                         512 + 16 * w + col};
#pragma unroll
    for (int rt = 0; rt < 5; ++rt) {
      const _Float16* rs = W16 + (size_t)rows[rt] * 256 + 8 * hi;
#pragma unroll
      for (int kt = 0; kt < 8; ++kt) afrag[rt][kt] = *(const f16x8*)(rs + 32 * kt);
    }
  }

  __shared__ __align__(16) _Float16 hb1[256];
  const int* chb = child + (size_t)b * 2 * N_;
  float* Hb = H + (size_t)b * N_ * U_;
  _Float16* Hb16 = H16 + (size_t)b * N_ * U_;
  _Float16* Cb16 = C16 + (size_t)b * N_ * U_;
  const _Float16* xzb = XZ + (size_t)b * N_ * Z_;

  for (int l = LPAR; l < LMAXT; ++l) {
    const int p0 = pos[l * 128 + b];
    const int n = cnt[l * 128 + b];
    for (int i = 0; i < n; ++i) {
      const int t = glist[p0 + i] & 1023;
      if (tid < 64) {
        const int ch = chb[2 * t + (m4 >> 7)];
        *(uint2*)&hb1[m4] =
            *(const uint2*)(Hb16 + ((size_t)ch << 7) + (m4 & 127));
      }
      const int cs = chb[2 * t + (mc >> 7)];
      const f16x8 cv16 =
          *(const f16x8*)(Cb16 + ((size_t)cs << 7) + (mc & 127));
      const _Float16* xzr = xzb + (size_t)t * Z_;
      const f16x4 xzi = *(const f16x4*)(xzr + u0);
      const f16x8 xzf = *(const f16x8*)(xzr + 128 + mc);
      const f16x4 xzo = *(const f16x4*)(xzr + 384 + u0);
      const f16x4 xzg = *(const f16x4*)(xzr + 512 + u0);
      __syncthreads();
      f32x4 acc[5];
#pragma unroll
      for (int r = 0; r < 4; ++r) {
        acc[0][r] = (float)xzi[r];
        acc[1][r] = (float)xzf[2 * r];
        acc[2][r] = (float)xzf[2 * r + 1];
        acc[3][r] = (float)xzo[r];
        acc[4][r] = (float)xzg[r];
      }
#pragma unroll
      for (int kt = 0; kt < 8; ++kt) {
        const f16x8 bf = *(const f16x8*)&hb1[32 * kt + 8 * hi];
#pragma unroll
        for (int rt = 0; rt < 5; ++rt)
          acc[rt] = __builtin_amdgcn_mfma_f32_16x16x32_f16(afrag[rt][kt], bf,
                                                           acc[rt], 0, 0, 0);
      }
      f32x4 hn4, cn4;
#pragma unroll
      for (int r = 0; r < 4; ++r) {
        const float cn = (float)cv16[2 * r] * hsig(acc[1][r]) +
                         (float)cv16[2 * r + 1] * hsig(acc[2][r]) +
                         hsig(acc[0][r]) * tanh_fast(acc[4][r]);
        cn4[r] = cn;
        hn4[r] = hsig(acc[3][r]) * tanh_fast(cn);
      }
      if (col == 0) {
        *(f32x4*)(Hb + ((size_t)t << 7) + u0) = hn4;
        uint2 hp16, cp16;
        hp16.x = pk2(hn4[0], hn4[1]);
        hp16.y = pk2(hn4[2], hn4[3]);
        cp16.x = pk2(cn4[0], cn4[1]);
        cp16.y = pk2(cn4[2], cn4[3]);
        *(uint2*)(Hb16 + ((size_t)t << 7) + u0) = hp16;
        *(uint2*)(Cb16 + ((size_t)t << 7) + u0) = cp16;
      }
      __syncthreads();
    }
  }
}

extern "C" void kernel_launch(void* const* d_in, const int* in_sizes, int n_in,
                              void* d_out, int out_size, void* d_ws,
                              size_t ws_size, hipStream_t stream) {
  const float* state = (const float*)d_in[0];
  const float* tk    = (const float*)d_in[1];
  const float* Wk    = (const float*)d_in[2];
  const float* Wr    = (const float*)d_in[3];
  const float* bias  = (const float*)d_in[4];
  const int*   child = (const int*)d_in[5];
  const int*   nvp   = (const int*)d_in[6];
  float* H = (float*)d_out;

  // meta (2 MiB): W16 | Wk16 | tkTb | lv | rank | cnt | pos | goff | glist
  char* wsb = (char*)d_ws;
  _Float16* W16   = (_Float16*)(wsb + 0x000000);  // 320K
  _Float16* Wk16  = (_Float16*)(wsb + 0x050000);  // 160K
  short* tkTb     = (short*)(wsb + 0x078000);     // 80K
  unsigned char* lv = (unsigned char*)(wsb + 0x08C000);  // 128K
  short* rank     = (short*)(wsb + 0x0AC000);            // 256K
  int* cnt        = (int*)(wsb + 0x0EC000);
  int* pos        = (int*)(wsb + 0x0F1000);
  int* goff       = (int*)(wsb + 0x0F6000);
  int* glist      = (int*)(wsb + 0x0F7000);              // 512K
  const size_t meta_sz = 2ull * 1024 * 1024;
  const size_t h16_bytes = (size_t)M_ * U_ * 2;  // 32 MiB each
  _Float16* H16 = (_Float16*)(wsb + meta_sz);
  _Float16* C16 = (_Float16*)(wsb + meta_sz + h16_bytes);
  _Float16* XZ  = (_Float16*)(wsb + meta_sz + 2 * h16_bytes);  // 160 MiB

  prep<<<1120, 256, 0, stream>>>(Wr, Wk, tk, W16, Wk16, tkTb);
  x_gemm<<<M_ / 64, 256, 0, stream>>>(state, tkTb, H);
  h16c16<<<(M_ * U_ / 8 + 255) / 256, 256, 0, stream>>>(H, H16, C16);
  xz_gemm<<<dim3(M_ / 64, 5), 256, 0, stream>>>(H, Wk16, bias, nvp, XZ);
  levelize<<<B_, 512, 0, stream>>>(child, nvp, lv, rank, cnt);
  offsets<<<1, 64, 0, stream>>>(cnt, pos, goff);
  scatter_zero<<<B_, 256, 0, stream>>>(nvp, lv, rank, pos, glist, H);
  static const int lg[LPAR] = {0,  512, 384, 256, 192, 128,
                               96, 64,  48,  32,  24,  20};
  for (int l = 1; l < LPAR; ++l)
    level_gemm<<<lg[l], 512, 0, stream>>>(l, W16, child, goff, glist, XZ, H,
                                          H16, C16);
  tail_scan<<<B_, 512, 0, stream>>>(W16, child, nvp, pos, cnt, glist, XZ, H,
                                    H16, C16);
}